// Round 6
// baseline (118.334 us; speedup 1.0000x reference)
//
#include <hip/hip_runtime.h>
#include <math.h>

typedef float v2f __attribute__((ext_vector_type(2)));

#define NN 1024
#define IN_F 256
#define OUT_F 128
#define NHEADS 4
#define NHF 32

// K1: FROZEN from round 5 (best so far, ~12 us). g_l/g_r = h @ W^T.
__global__ void __launch_bounds__(256) glr_gemm(const float* __restrict__ hmat,
                                                const float* __restrict__ Wl,
                                                const float* __restrict__ Wr,
                                                v2f* __restrict__ glT,
                                                float* __restrict__ grh) {
    __shared__ float hs[64 * 132];   // 33.8 KB
    const int tid  = threadIdx.x;
    const int rg   = blockIdx.x;     // 0..15
    const int cs   = blockIdx.y;     // 0..31
    const int lane = tid & 63;
    const int wu   = __builtin_amdgcn_readfirstlane(tid >> 6);
    const int c0   = cs * 8 + wu * 2;
    const int half = c0 >> 7;
    const int cc   = c0 & 127;
    const float* __restrict__ W   = half ? Wr : Wl;
    const float* __restrict__ wr0 = W + cc * IN_F;
    const float* __restrict__ wr1 = wr0 + IN_F;

    float a0 = 0.f, a1 = 0.f;
    for (int kh = 0; kh < 2; ++kh) {
#pragma unroll
        for (int s = 0; s < 8; ++s) {
            const int v = tid + s * 256;
            const int row = v >> 5, q = v & 31;
            const float4 x = ((const float4*)hmat)[(rg * 64 + row) * 64 + kh * 32 + q];
            *(float4*)(hs + row * 132 + q * 4) = x;
        }
        __syncthreads();
        const float4* __restrict__ w0p = (const float4*)(wr0 + kh * 128);
        const float4* __restrict__ w1p = (const float4*)(wr1 + kh * 128);
        const float*  __restrict__ hrow = hs + lane * 132;
#pragma unroll 8
        for (int q = 0; q < 32; ++q) {
            const float4 hv = *(const float4*)(hrow + q * 4);
            const float4 w0 = w0p[q];
            const float4 w1 = w1p[q];
            a0 = fmaf(hv.x, w0.x, fmaf(hv.y, w0.y, fmaf(hv.z, w0.z, fmaf(hv.w, w0.w, a0))));
            a1 = fmaf(hv.x, w1.x, fmaf(hv.y, w1.y, fmaf(hv.z, w1.z, fmaf(hv.w, w1.w, a1))));
        }
        __syncthreads();
    }

    const int row = rg * 64 + lane;
    const int hh = cc >> 5, f0 = cc & 31;
    if (half == 0) {
        glT[(hh * 16 + (f0 >> 1)) * NN + row] = (v2f){a0, a1};
    } else {
        *(v2f*)(grh + (hh * NN + row) * NHF + f0) = (v2f){a0, a1};
    }
}

// K2 rewritten: wave <-> ii (one attention row per wave).
//  - gr fragment preloaded ONCE into 32 VGPRs (wave-uniform addr) -> the
//    48-pk-op inner block has no memory dependence except the gl stream.
//  - alpha_j precomputed cooperatively into LDS (A0 pass).
//  - p_buf[ii][1024]: every access lane-contiguous b32, conflict-free.
//  - Phase C: 128-j LDS g_r tiles, stride 33 (b128 bank-optimal); wave<->f-quad,
//    8 ii in registers; 6-round butterfly epilogue.
__global__ void __launch_bounds__(512, 4) gat_main(const v2f* __restrict__ glT,
                                                   const float* __restrict__ grh,
                                                   const int* __restrict__ adj,
                                                   const float* __restrict__ attn_w,
                                                   float* __restrict__ out) {
    const int hh   = blockIdx.y;
    const int i0   = blockIdx.x * 8;
    const int tid  = threadIdx.x;
    const int lane = tid & 63;
    const int wv   = __builtin_amdgcn_readfirstlane(tid >> 6);

    __shared__ float p_buf[8][NN];    // 32 KB
    __shared__ float alpha_s[NN];     // 4 KB
    __shared__ float g_t[128 * 33];   // 16.9 KB
    __shared__ float l_sh[8];

    const v2f* __restrict__ w2p    = (const v2f*)attn_w;
    const v2f* __restrict__ glbase = glT + hh * 16 * NN;

    // ---- A0: alpha_j = 0.6 * dot(w, gl_j) cooperatively ----
#pragma unroll
    for (int c = 0; c < 2; ++c) {
        const int j = (c << 9) + tid;
        const v2f* __restrict__ glp = glbase + j;
        v2f aa = {0.f, 0.f};
#pragma unroll
        for (int fp = 0; fp < 16; ++fp) aa += glp[fp * NN] * w2p[fp];
        alpha_s[j] = 0.6f * (aa.x + aa.y);
    }

    // preload g_r row for this wave's ii (wave-uniform address, 16 loads, once)
    const v2f* __restrict__ gr2 = (const v2f*)(grh + (hh * NN + i0 + wv) * NHF);
    v2f grr[16];
#pragma unroll
    for (int fp = 0; fp < 16; ++fp) grr[fp] = gr2[fp];

    __syncthreads();

    // ---- Phase A main: e -> p, fused exp + row-sum ----
    const int* __restrict__ adjrow = adj + (i0 + wv) * NN;
    float lsum = 0.f;
    for (int t = 0; t < 16; ++t) {
        const int j = (t << 6) + lane;
        const v2f* __restrict__ glp = glbase + j;
        v2f gl2[16];
#pragma unroll
        for (int fp = 0; fp < 16; ++fp) gl2[fp] = glp[fp * NN];   // coalesced 8B/lane
        const int ad = adjrow[j];
        v2f S = {0.f, 0.f};
#pragma unroll
        for (int fp = 0; fp < 16; ++fp) {
            const v2f s = gl2[fp] + grr[fp];                 // regs only
            const v2f m = __builtin_elementwise_max(s, -s);  // |s| via pk_max neg-mod
            S += m * w2p[fp];
        }
        const float e = fmaf(0.4f, S.x + S.y, alpha_s[j]);
        const float p = ad ? __expf(e) : 0.f;
        p_buf[wv][j] = p;                                    // lane-contiguous
        lsum += p;
    }
#pragma unroll
    for (int d = 32; d > 0; d >>= 1) lsum += __shfl_xor(lsum, d);
    if (lane == 0) l_sh[wv] = lsum;

    // ---- Phase C: o[ii,f] = sum_j p * g_r ----
    v2f acc[8][2];
#pragma unroll
    for (int ii = 0; ii < 8; ++ii) { acc[ii][0] = (v2f){0.f, 0.f}; acc[ii][1] = (v2f){0.f, 0.f}; }

    const float4* __restrict__ gsrc = (const float4*)(grh + hh * NN * NHF);
    for (int t = 0; t < 8; ++t) {
        __syncthreads();                      // prev tile readers done (and p_buf ready at t=0)
#pragma unroll
        for (int s2 = 0; s2 < 2; ++s2) {
            const int u = tid + (s2 << 9);    // 1024 float4 = 128 j x 32 f
            const int jj = u >> 3, f4 = u & 7;
            const float4 x = gsrc[(t << 10) + u];
            *(float4*)&g_t[jj * 33 + (f4 << 2)] = x;
        }
        __syncthreads();
#pragma unroll
        for (int u2 = 0; u2 < 2; ++u2) {
            const int jl = lane + (u2 << 6);
            const float4 g = *(const float4*)&g_t[jl * 33 + (wv << 2)];  // stride 33: optimal
            const int jg = (t << 7) + jl;
            float pv[8];
#pragma unroll
            for (int ii = 0; ii < 8; ++ii) pv[ii] = p_buf[ii][jg];       // lane-contiguous
            const v2f g01 = {g.x, g.y}, g23 = {g.z, g.w};
#pragma unroll
            for (int ii = 0; ii < 8; ++ii) {
                const v2f pp = {pv[ii], pv[ii]};
                acc[ii][0] += pp * g01;
                acc[ii][1] += pp * g23;
            }
        }
    }

    // butterfly over 64 j-lanes (waves own disjoint f-quads)
    float o32[32];
#pragma unroll
    for (int ii = 0; ii < 8; ++ii) {
        o32[ii * 4 + 0] = acc[ii][0].x;  o32[ii * 4 + 1] = acc[ii][0].y;
        o32[ii * 4 + 2] = acc[ii][1].x;  o32[ii * 4 + 3] = acc[ii][1].y;
    }
#pragma unroll
    for (int d = 32; d > 0; d >>= 1) {
#pragma unroll
        for (int k = 0; k < 32; ++k) o32[k] += __shfl_xor(o32[k], d);
    }
    if (lane == 0) {
#pragma unroll
        for (int ii = 0; ii < 8; ++ii) {
            const float inv = 1.f / l_sh[ii];
            const float x0 = o32[ii * 4 + 0] * inv;
            const float x1 = o32[ii * 4 + 1] * inv;
            const float x2 = o32[ii * 4 + 2] * inv;
            const float x3 = o32[ii * 4 + 3] * inv;
            float4 r;
            r.x = (x0 > 0.f) ? x0 : (__expf(x0) - 1.f);
            r.y = (x1 > 0.f) ? x1 : (__expf(x1) - 1.f);
            r.z = (x2 > 0.f) ? x2 : (__expf(x2) - 1.f);
            r.w = (x3 > 0.f) ? x3 : (__expf(x3) - 1.f);
            *(float4*)(out + (i0 + ii) * OUT_F + hh * NHF + (wv << 2)) = r;
        }
    }
}

extern "C" void kernel_launch(void* const* d_in, const int* in_sizes, int n_in,
                              void* d_out, int out_size, void* d_ws, size_t ws_size,
                              hipStream_t stream) {
    const float* hmat = (const float*)d_in[0];
    const int*   adj  = (const int*)d_in[1];
    const float* Wl   = (const float*)d_in[2];
    const float* Wr   = (const float*)d_in[3];
    const float* aw   = (const float*)d_in[4];
    float* o          = (float*)d_out;

    float* wsf = (float*)d_ws;
    v2f*   glT = (v2f*)wsf;                        // [4][16][1024] v2f
    float* grh = wsf + NHEADS * 16 * NN * 2;       // [4][1024][32]

    glr_gemm<<<dim3(16, 32), dim3(256), 0, stream>>>(hmat, Wl, Wr, glT, grh);
    gat_main<<<dim3(NN / 8, NHEADS), dim3(512), 0, stream>>>(glT, grh, adj, aw, o);
}